// Round 6
// baseline (16211.224 us; speedup 1.0000x reference)
//
#include <hip/hip_runtime.h>
#include <math.h>

#define T_STEPS 4096
#define HID     2048
#define MOD     256
#define INSZ    1024
#define NWAVE   256            // one wave per block, one block per CU
#define NREP    16             // comm replicas; wave g polls replica g>>4

// ---------------------------------------------------------------------------
// Agent-scope (device-coherent, sc1) helpers — serviced at the coherence
// point, bypassing the non-coherent per-XCD L2s. Relaxed: no fences.
// ---------------------------------------------------------------------------
static __device__ __forceinline__ unsigned long long agent_load_u64(
        const unsigned long long* p) {
    return __hip_atomic_load((unsigned long long*)p, __ATOMIC_RELAXED,
                             __HIP_MEMORY_SCOPE_AGENT);
}
static __device__ __forceinline__ void agent_store_u64(
        unsigned long long* p, unsigned long long v) {
    __hip_atomic_store(p, v, __ATOMIC_RELAXED, __HIP_MEMORY_SCOPE_AGENT);
}

// ---------------------------------------------------------------------------
// Kernel 1: U = x @ W_ih^T + (b_ih + b_hh), written into out[t, i].
// 128x128 tile, BK=8, 256 threads, 8x8 per thread, fp32.
// ---------------------------------------------------------------------------
#define BM 128
#define BN 128
#define BK 8

__global__ __launch_bounds__(256) void gemm_u(
    const float* __restrict__ x, const float* __restrict__ Wih,
    const float* __restrict__ bih, const float* __restrict__ bhh,
    float* __restrict__ out)
{
    __shared__ float As[BK][BM];
    __shared__ float Bs[BK][BN];

    const int tid = threadIdx.x;
    const int t0 = blockIdx.y * BM;
    const int i0 = blockIdx.x * BN;
    const int tx = tid & 15;
    const int ty = tid >> 4;
    const int arow = tid >> 1;
    const int acol = (tid & 1) * 4;

    float acc[8][8];
#pragma unroll
    for (int a = 0; a < 8; ++a)
#pragma unroll
        for (int b = 0; b < 8; ++b) acc[a][b] = 0.0f;

    for (int k0 = 0; k0 < INSZ; k0 += BK) {
        float4 av = *(const float4*)(x   + (size_t)(t0 + arow) * INSZ + k0 + acol);
        float4 bv = *(const float4*)(Wih + (size_t)(i0 + arow) * INSZ + k0 + acol);
        __syncthreads();
        As[acol + 0][arow] = av.x; As[acol + 1][arow] = av.y;
        As[acol + 2][arow] = av.z; As[acol + 3][arow] = av.w;
        Bs[acol + 0][arow] = bv.x; Bs[acol + 1][arow] = bv.y;
        Bs[acol + 2][arow] = bv.z; Bs[acol + 3][arow] = bv.w;
        __syncthreads();
#pragma unroll
        for (int kk = 0; kk < BK; ++kk) {
            float a[8], b[8];
            *(float4*)&a[0] = *(const float4*)&As[kk][ty * 8];
            *(float4*)&a[4] = *(const float4*)&As[kk][ty * 8 + 4];
            *(float4*)&b[0] = *(const float4*)&Bs[kk][tx * 8];
            *(float4*)&b[4] = *(const float4*)&Bs[kk][tx * 8 + 4];
#pragma unroll
            for (int ri = 0; ri < 8; ++ri)
#pragma unroll
                for (int ci = 0; ci < 8; ++ci)
                    acc[ri][ci] = fmaf(a[ri], b[ci], acc[ri][ci]);
        }
    }

    float bias[8];
#pragma unroll
    for (int ci = 0; ci < 8; ++ci) {
        int i = i0 + tx * 8 + ci;
        bias[ci] = bih[i] + bhh[i];
    }
#pragma unroll
    for (int ri = 0; ri < 8; ++ri) {
        int t = t0 + ty * 8 + ri;
#pragma unroll
        for (int ci = 0; ci < 8; ++ci) {
            int i = i0 + tx * 8 + ci;
            out[(size_t)t * HID + i] = acc[ri][ci] + bias[ci];
        }
    }
}

// ---------------------------------------------------------------------------
// Kernel 2: persistent recurrence, barrier-free, 16x-replicated comm.
// 256 blocks x 64 threads (one wave per CU). Full h in registers (lane l
// holds cols 256j+4l..+3). Exchange = self-validating (tag<<32|bits)
// packets, replicated into 16 copies; wave g polls only replica g>>4, so
// each comm cache line has 16 readers instead of 256 (LLC hot-line fix).
// The butterfly reduce leaves the sum in all lanes, so lanes 0..15 publish
// the 16 replicas with one store each. Parity-reuse induction as before:
// consuming module-0 tag (t-1) certifies every wave passed its publish
// point for t-1, hence finished all tag-(t-2) reads.
// ---------------------------------------------------------------------------
__global__ __launch_bounds__(64, 1) void cwrnn_rec(
    float* __restrict__ out, const float* __restrict__ Whh,
    unsigned long long* __restrict__ comm)
{
    const int lane = threadIdx.x;        // 0..63
    const int g    = blockIdx.x;         // wave id 0..255 == owned module-0 row
    const int grp  = g >> 4;             // replica this wave polls

    // register h(0) = 0 : hreg[j] = h[256j + 4*lane .. +3]
    float4 hreg[8];
#pragma unroll
    for (int j = 0; j < 8; ++j) hreg[j] = make_float4(0.f, 0.f, 0.f, 0.f);

    // cache W_hh[g, :] with matching fragment layout: w0[j] = W[g][256j+4l..+3]
    float4 w0[8];
    {
        const float4* wr = (const float4*)(Whh + (size_t)g * HID);
#pragma unroll
        for (int j = 0; j < 8; ++j) w0[j] = wr[lane + 64 * j];
    }

    for (int t = 1; t <= T_STEPS; ++t) {
        const int ctz = __builtin_ctz(t);
        const int A = (ctz + 1 > 8) ? 8 : (ctz + 1);
        float* orow = out + (size_t)(t - 1) * HID;

        // U prefetch: lane m (< A) grabs U for row m*256+g (gemm output)
        float upf = (lane < A) ? orow[lane * MOD + g] : 0.0f;

        // --- refresh register-h prefix from replica `grp`: one retry loop,
        // all loads issued back-to-back (single round trip per round)
        if (t > 1) {
            const int ctzp = __builtin_ctz(t - 1);
            const int Ap = (ctzp + 1 > 8) ? 8 : (ctzp + 1);
            const unsigned need = (unsigned)(t - 1);
            const unsigned long long* csrc =
                comm + (size_t)(grp * 2 + ((t - 1) & 1)) * HID + 4 * lane;
            unsigned long long pv[8][4];
            for (;;) {
#pragma unroll
                for (int j = 0; j < 8; ++j) {
                    if (j < Ap) {
                        pv[j][0] = agent_load_u64(csrc + j * MOD + 0);
                        pv[j][1] = agent_load_u64(csrc + j * MOD + 1);
                        pv[j][2] = agent_load_u64(csrc + j * MOD + 2);
                        pv[j][3] = agent_load_u64(csrc + j * MOD + 3);
                    }
                }
                bool ok = true;
#pragma unroll
                for (int j = 0; j < 8; ++j) {
                    if (j < Ap)
                        ok = ok && ((unsigned)(pv[j][0] >> 32) >= need)
                                && ((unsigned)(pv[j][1] >> 32) >= need)
                                && ((unsigned)(pv[j][2] >> 32) >= need)
                                && ((unsigned)(pv[j][3] >> 32) >= need);
                }
                if (ok) break;
            }
#pragma unroll
            for (int j = 0; j < 8; ++j) {
                if (j < Ap)
                    hreg[j] = make_float4(
                        __uint_as_float((unsigned)pv[j][0]),
                        __uint_as_float((unsigned)pv[j][1]),
                        __uint_as_float((unsigned)pv[j][2]),
                        __uint_as_float((unsigned)pv[j][3]));
            }
        }

        const size_t pbase = (size_t)(t & 1) * HID;   // parity offset in replica
        const unsigned long long tagbits =
            ((unsigned long long)(unsigned)t) << 32;

        // --- owned module-0 row: all-register dot; butterfly leaves acc in
        // every lane, so all lanes form hv and lanes 0..15 publish replicas.
        {
            float4 s = make_float4(0.f, 0.f, 0.f, 0.f);
#pragma unroll
            for (int j = 0; j < 8; ++j) {
                s.x = fmaf(w0[j].x, hreg[j].x, s.x);
                s.y = fmaf(w0[j].y, hreg[j].y, s.y);
                s.z = fmaf(w0[j].z, hreg[j].z, s.z);
                s.w = fmaf(w0[j].w, hreg[j].w, s.w);
            }
            float acc = (s.x + s.y) + (s.z + s.w);
#pragma unroll
            for (int off = 32; off; off >>= 1) acc += __shfl_xor(acc, off, 64);
            float u0 = __shfl(upf, 0, 64);
            float hv = tanhf(u0 + acc);
            unsigned long long pkt =
                tagbits | (unsigned long long)__float_as_uint(hv);
            if (lane < NREP)
                agent_store_u64(comm + (size_t)(lane * 2) * HID + pbase + g, pkt);
            if (lane == 0) orow[g] = hv;
        }

        // --- streamed rows (modules 1..A-1), pairs for load-level parallelism
        int m = 1;
        for (; m + 1 < A; m += 2) {
            const int ra = m * MOD + g;
            const int rb = ra + MOD;
            const float4* wa = (const float4*)(Whh + (size_t)ra * HID);
            const float4* wb = (const float4*)(Whh + (size_t)rb * HID);
            float4 sa = make_float4(0.f, 0.f, 0.f, 0.f);
            float4 sb = make_float4(0.f, 0.f, 0.f, 0.f);
#pragma unroll
            for (int j = 0; j < 8; ++j) {
                float4 a = wa[lane + 64 * j];
                float4 b = wb[lane + 64 * j];
                sa.x = fmaf(a.x, hreg[j].x, sa.x);
                sa.y = fmaf(a.y, hreg[j].y, sa.y);
                sa.z = fmaf(a.z, hreg[j].z, sa.z);
                sa.w = fmaf(a.w, hreg[j].w, sa.w);
                sb.x = fmaf(b.x, hreg[j].x, sb.x);
                sb.y = fmaf(b.y, hreg[j].y, sb.y);
                sb.z = fmaf(b.z, hreg[j].z, sb.z);
                sb.w = fmaf(b.w, hreg[j].w, sb.w);
            }
            float acca = (sa.x + sa.y) + (sa.z + sa.w);
            float accb = (sb.x + sb.y) + (sb.z + sb.w);
#pragma unroll
            for (int off = 32; off; off >>= 1) {
                acca += __shfl_xor(acca, off, 64);
                accb += __shfl_xor(accb, off, 64);
            }
            float ua = __shfl(upf, m, 64);
            float ub = __shfl(upf, m + 1, 64);
            float hva = tanhf(ua + acca);
            float hvb = tanhf(ub + accb);
            unsigned long long pa =
                tagbits | (unsigned long long)__float_as_uint(hva);
            unsigned long long pb =
                tagbits | (unsigned long long)__float_as_uint(hvb);
            if (lane < NREP) {
                unsigned long long* rb_ = comm + (size_t)(lane * 2) * HID + pbase;
                agent_store_u64(rb_ + ra, pa);
                agent_store_u64(rb_ + rb, pb);
            }
            if (lane == 0) { orow[ra] = hva; orow[rb] = hvb; }
        }
        if (m < A) {                                 // tail single row
            const int r = m * MOD + g;
            const float4* wr = (const float4*)(Whh + (size_t)r * HID);
            float4 s = make_float4(0.f, 0.f, 0.f, 0.f);
#pragma unroll
            for (int j = 0; j < 8; ++j) {
                float4 a = wr[lane + 64 * j];
                s.x = fmaf(a.x, hreg[j].x, s.x);
                s.y = fmaf(a.y, hreg[j].y, s.y);
                s.z = fmaf(a.z, hreg[j].z, s.z);
                s.w = fmaf(a.w, hreg[j].w, s.w);
            }
            float acc = (s.x + s.y) + (s.z + s.w);
#pragma unroll
            for (int off = 32; off; off >>= 1) acc += __shfl_xor(acc, off, 64);
            float um = __shfl(upf, m, 64);
            float hv = tanhf(um + acc);
            unsigned long long pkt =
                tagbits | (unsigned long long)__float_as_uint(hv);
            if (lane < NREP)
                agent_store_u64(comm + (size_t)(lane * 2) * HID + pbase + r, pkt);
            if (lane == 0) orow[r] = hv;
        }

        // --- inactive rows: wave (j - A) writes module j from its registers
#pragma unroll
        for (int j = 0; j < 8; ++j) {
            if (j >= A && g == (j - A)) {
                *(float4*)(orow + j * MOD + 4 * lane) = hreg[j];
            }
        }
    }
}

// ---------------------------------------------------------------------------
extern "C" void kernel_launch(void* const* d_in, const int* in_sizes, int n_in,
                              void* d_out, int out_size, void* d_ws, size_t ws_size,
                              hipStream_t stream) {
    const float* x   = (const float*)d_in[0];
    const float* Wih = (const float*)d_in[1];
    const float* Whh = (const float*)d_in[2];
    const float* bih = (const float*)d_in[3];
    const float* bhh = (const float*)d_in[4];
    float* out = (float*)d_out;
    unsigned long long* comm = (unsigned long long*)d_ws;

    // tags must start at 0: 16 replicas x 2 parities x 2048 x 8B = 512 KB
    hipMemsetAsync(d_ws, 0, (size_t)NREP * 2 * HID * sizeof(unsigned long long),
                   stream);

    dim3 g1(HID / BN, T_STEPS / BM);        // (16, 32)
    gemm_u<<<g1, 256, 0, stream>>>(x, Wih, bih, bhh, out);
    cwrnn_rec<<<NWAVE, 64, 0, stream>>>(out, Whh, comm);
}